// Round 2
// baseline (1195.528 us; speedup 1.0000x reference)
//
#include <hip/hip_runtime.h>
#include <hip/hip_bf16.h>

#define BATCH 256
#define FIN 2048
#define D 8192
#define DH 4096
#define NC 14951

typedef __attribute__((ext_vector_type(8))) short short8;
typedef __attribute__((ext_vector_type(4))) float f32x4;

__device__ __forceinline__ unsigned short f2bf(float f) {
    unsigned u = __float_as_uint(f);
    u += 0x7FFFu + ((u >> 16) & 1u);
    return (unsigned short)(u >> 16);
}
__device__ __forceinline__ float bf2f(unsigned short h) {
    return __uint_as_float(((unsigned)h) << 16);
}

// ---------------- kernel 0: twiddle table tw[m] = exp(-2*pi*i*m/D) ----------
__global__ void twiddle_kernel(float2* __restrict__ tw) {
    int i = blockIdx.x * blockDim.x + threadIdx.x;
    if (i < DH) {
        double ang = -2.0 * 3.14159265358979323846 * (double)i / (double)D;
        tw[i] = make_float2((float)cos(ang), (float)sin(ang));
    }
}

// ---------------- kernel 1: sketch + FFT + pointwise + IFFT + bf16 split ----
// z = sk1 + i*sk2 packed-real FFT trick; Stockham autosort (no bit reversal).
__global__ __launch_bounds__(1024) void cbp_kernel(
    const float* __restrict__ x, const int* __restrict__ h1, const int* __restrict__ h2,
    const float* __restrict__ s1, const float* __restrict__ s2,
    const float2* __restrict__ tw,
    unsigned short* __restrict__ Ah, unsigned short* __restrict__ Al)
{
    __shared__ float2 bufX[D];
    __shared__ float2 bufY[D];
    const int b = blockIdx.x;
    const int tid = threadIdx.x;
    const int NT = 1024;

    for (int i = tid; i < D; i += NT) bufX[i] = make_float2(0.f, 0.f);
    __syncthreads();

    // count-sketch scatter with LDS atomics (sk1 in .x, sk2 in .y)
    const float* xrow = x + (size_t)b * FIN;
    for (int i = tid; i < FIN; i += NT) {
        float v = xrow[i];
        atomicAdd(&bufX[h1[i]].x, s1[i] * v);
        atomicAdd(&bufX[h2[i]].y, s2[i] * v);
    }
    __syncthreads();

    float2* src = bufX;
    float2* dst = bufY;

    // forward FFT: 13 Stockham radix-2 stages
    for (int ns = 1; ns < D; ns <<= 1) {
        const int tscale = DH / ns;
        for (int i = tid; i < DH; i += NT) {
            int j = i & (ns - 1);
            float2 a = src[i];
            float2 c = src[i + DH];
            float2 w = tw[j * tscale];
            float wcx = w.x * c.x - w.y * c.y;
            float wcy = w.x * c.y + w.y * c.x;
            int d0 = i + (i & ~(ns - 1));
            dst[d0]      = make_float2(a.x + wcx, a.y + wcy);
            dst[d0 + ns] = make_float2(a.x - wcx, a.y - wcy);
        }
        __syncthreads();
        float2* t = src; src = dst; dst = t;
    }

    // Hermitian split + pointwise product P[k] = F1[k]*F2[k]
    for (int k = tid; k < D; k += NT) {
        float2 zk = src[k];
        float2 zm = src[(D - k) & (D - 1)];
        float f1x = 0.5f * (zk.x + zm.x);
        float f1y = 0.5f * (zk.y - zm.y);
        float gx  = 0.5f * (zk.x - zm.x);
        float gy  = 0.5f * (zk.y + zm.y);
        float f2x = gy, f2y = -gx;   // F2 = -i*(gx + i*gy)
        dst[k] = make_float2(f1x * f2x - f1y * f2y, f1x * f2y + f1y * f2x);
    }
    __syncthreads();
    { float2* t = src; src = dst; dst = t; }

    // inverse FFT: conjugated twiddles; result = D * idft
    for (int ns = 1; ns < D; ns <<= 1) {
        const int tscale = DH / ns;
        for (int i = tid; i < DH; i += NT) {
            int j = i & (ns - 1);
            float2 a = src[i];
            float2 c = src[i + DH];
            float2 w = tw[j * tscale];
            float wy = -w.y;
            float wcx = w.x * c.x - wy * c.y;
            float wcy = w.x * c.y + wy * c.x;
            int d0 = i + (i & ~(ns - 1));
            dst[d0]      = make_float2(a.x + wcx, a.y + wcy);
            dst[d0 + ns] = make_float2(a.x - wcx, a.y - wcy);
        }
        __syncthreads();
        float2* t = src; src = dst; dst = t;
    }

    // cbp row = Re(src)/D; emit split bf16 hi/lo
    const float invD = 1.0f / (float)D;
    unsigned short* ah = Ah + (size_t)b * D;
    unsigned short* al = Al + (size_t)b * D;
    for (int t = tid; t < D; t += NT) {
        float v = src[t].x * invD;
        unsigned short h = f2bf(v);
        unsigned short l = f2bf(v - bf2f(h));
        ah[t] = h;
        al[t] = l;
    }
}

// ---------------- kernel 2: GEMM out[m,n] = sum_k cbp[m,k]*W[n,k] + b[n] ----
// 512 thr / 8 waves (4M x 2N), block 256x64, wave 64x32, K_step 64.
// A-hi + B-hi/lo staged in LDS; A-lo fragments read direct from global (L2).
// 3-term split product: Ah*Bh + Ah*Bl + Al*Bh.
#define NTILE 64
#define KS 64
#define LROW 72   // 64 + 8 pad elements -> 144B rows, 16B-aligned, uniform stripes

__global__ __launch_bounds__(512, 2) void gemm_kernel(
    const unsigned short* __restrict__ Ah, const unsigned short* __restrict__ Al,
    const float* __restrict__ W, const float* __restrict__ bias,
    float* __restrict__ out)
{
    __shared__ __align__(16) unsigned short lAh[256 * LROW];  // 36864 B
    __shared__ __align__(16) unsigned short lBh[NTILE * LROW]; // 9216 B
    __shared__ __align__(16) unsigned short lBl[NTILE * LROW]; // 9216 B

    const int tid = threadIdx.x;
    const int n0 = blockIdx.x * NTILE;
    const int wave = tid >> 6;        // 0..7
    const int lane = tid & 63;
    const int wm = wave >> 1;         // 0..3 -> rows 64*wm
    const int wn = wave & 1;          // 0..1 -> cols 32*wn

    // staging decomposition
    const int arow = tid >> 1;            // 0..255 (A rows)
    const int ahalf = tid & 1;            // which 32-elem half of the 64-k row
    const int bn   = tid >> 3;            // 0..63 (B rows)
    const int bk   = (tid & 7) * 8;       // f32 index within KS

    f32x4 acc[4][2];
#pragma unroll
    for (int i = 0; i < 4; ++i)
#pragma unroll
        for (int j = 0; j < 2; ++j) acc[i][j] = (f32x4){0.f, 0.f, 0.f, 0.f};

    uint4 pah[4];
    float4 pbw[2];

    auto LOAD = [&](int k0) {
        const uint4* gah = reinterpret_cast<const uint4*>(Ah + (size_t)arow * D + k0 + ahalf * 32);
#pragma unroll
        for (int c = 0; c < 4; ++c) pah[c] = gah[c];
        int n = n0 + bn;
        if (n < NC) {
            const float4* gw = reinterpret_cast<const float4*>(W + (size_t)n * D + k0 + bk);
            pbw[0] = gw[0];
            pbw[1] = gw[1];
        } else {
            pbw[0] = make_float4(0.f, 0.f, 0.f, 0.f);
            pbw[1] = make_float4(0.f, 0.f, 0.f, 0.f);
        }
    };

    auto STORE = [&]() {
#pragma unroll
        for (int c = 0; c < 4; ++c)
            *reinterpret_cast<uint4*>(&lAh[arow * LROW + ahalf * 32 + c * 8]) = pah[c];
        unsigned short h[8], l[8];
        const float* pf = reinterpret_cast<const float*>(pbw);
#pragma unroll
        for (int j = 0; j < 8; ++j) {
            h[j] = f2bf(pf[j]);
            l[j] = f2bf(pf[j] - bf2f(h[j]));
        }
        uint4 hv, lv;
        hv.x = (unsigned)h[0] | ((unsigned)h[1] << 16);
        hv.y = (unsigned)h[2] | ((unsigned)h[3] << 16);
        hv.z = (unsigned)h[4] | ((unsigned)h[5] << 16);
        hv.w = (unsigned)h[6] | ((unsigned)h[7] << 16);
        lv.x = (unsigned)l[0] | ((unsigned)l[1] << 16);
        lv.y = (unsigned)l[2] | ((unsigned)l[3] << 16);
        lv.z = (unsigned)l[4] | ((unsigned)l[5] << 16);
        lv.w = (unsigned)l[6] | ((unsigned)l[7] << 16);
        *reinterpret_cast<uint4*>(&lBh[bn * LROW + bk]) = hv;
        *reinterpret_cast<uint4*>(&lBl[bn * LROW + bk]) = lv;
    };

    const int r16 = lane & 15;
    const int q8  = (lane >> 4) * 8;   // k element offset within 32-k group

    LOAD(0);
    for (int k0 = 0; k0 < D; k0 += KS) {
        __syncthreads();   // previous compute done before LDS overwrite
        STORE();
        __syncthreads();
        if (k0 + KS < D) LOAD(k0 + KS);   // prefetch next tile into regs

#pragma unroll
        for (int ksub = 0; ksub < 2; ++ksub) {
            const int ke = ksub * 32 + q8;
            // A-lo fragments direct from global (Al is L2/LLC-resident, 4 MB)
            short8 alo[4];
#pragma unroll
            for (int rb = 0; rb < 4; ++rb) {
                const int row = wm * 64 + rb * 16 + r16;
                alo[rb] = *reinterpret_cast<const short8*>(Al + (size_t)row * D + k0 + ke);
            }
            short8 bh[2], bl[2];
#pragma unroll
            for (int nb = 0; nb < 2; ++nb) {
                const int brow = wn * 32 + nb * 16 + r16;
                bh[nb] = *reinterpret_cast<const short8*>(&lBh[brow * LROW + ke]);
                bl[nb] = *reinterpret_cast<const short8*>(&lBl[brow * LROW + ke]);
            }
#pragma unroll
            for (int rb = 0; rb < 4; ++rb) {
                const int row = wm * 64 + rb * 16 + r16;
                short8 ahi = *reinterpret_cast<const short8*>(&lAh[row * LROW + ke]);
#pragma unroll
                for (int nb = 0; nb < 2; ++nb) {
                    acc[rb][nb] = __builtin_amdgcn_mfma_f32_16x16x32_bf16(ahi, bh[nb], acc[rb][nb], 0, 0, 0);
                    acc[rb][nb] = __builtin_amdgcn_mfma_f32_16x16x32_bf16(ahi, bl[nb], acc[rb][nb], 0, 0, 0);
                    acc[rb][nb] = __builtin_amdgcn_mfma_f32_16x16x32_bf16(alo[rb], bh[nb], acc[rb][nb], 0, 0, 0);
                }
            }
        }
    }

    // epilogue: C/D map col = lane&15, row = (lane>>4)*4 + reg (verified gfx950)
    const int rquad = (lane >> 4) * 4;
#pragma unroll
    for (int nb = 0; nb < 2; ++nb) {
        const int nc = n0 + wn * 32 + nb * 16 + r16;
        if (nc < NC) {
            const float bv = bias[nc];
#pragma unroll
            for (int rb = 0; rb < 4; ++rb) {
#pragma unroll
                for (int r = 0; r < 4; ++r) {
                    int m = wm * 64 + rb * 16 + rquad + r;
                    out[(size_t)m * NC + nc] = acc[rb][nb][r] + bv;
                }
            }
        }
    }
}

extern "C" void kernel_launch(void* const* d_in, const int* in_sizes, int n_in,
                              void* d_out, int out_size, void* d_ws, size_t ws_size,
                              hipStream_t stream) {
    const float* x  = (const float*)d_in[0];
    const int*   h1 = (const int*)d_in[1];
    const int*   h2 = (const int*)d_in[2];
    const float* s1 = (const float*)d_in[3];
    const float* s2 = (const float*)d_in[4];
    const float* W  = (const float*)d_in[5];
    const float* bias = (const float*)d_in[6];
    float* out = (float*)d_out;

    const size_t TW_BYTES = (size_t)DH * sizeof(float2);                 // 32 KB
    const size_t A_BYTES  = (size_t)BATCH * D * sizeof(unsigned short);  // 4 MB
    if (ws_size < TW_BYTES + 2 * A_BYTES) return;  // insufficient scratch

    float2* tw = (float2*)d_ws;
    unsigned short* Ah = (unsigned short*)((char*)d_ws + TW_BYTES);
    unsigned short* Al = (unsigned short*)((char*)d_ws + TW_BYTES + A_BYTES);

    twiddle_kernel<<<dim3(4), dim3(1024), 0, stream>>>(tw);
    cbp_kernel<<<dim3(BATCH), dim3(1024), 0, stream>>>(x, h1, h2, s1, s2, tw, Ah, Al);
    const int nblocks = (NC + NTILE - 1) / NTILE;  // 234
    gemm_kernel<<<dim3(nblocks), dim3(512), 0, stream>>>(Ah, Al, W, bias, out);
}

// Round 4
// 784.094 us; speedup vs baseline: 1.5247x; 1.5247x over previous
//
#include <hip/hip_runtime.h>
#include <hip/hip_bf16.h>

#define BATCH 256
#define FIN 2048
#define D 8192
#define NC 14951

typedef __attribute__((ext_vector_type(8))) short short8;
typedef __attribute__((ext_vector_type(4))) float f32x4;

__device__ __forceinline__ unsigned short f2bf(float f) {
    unsigned u = __float_as_uint(f);
    u += 0x7FFFu + ((u >> 16) & 1u);
    return (unsigned short)(u >> 16);
}
__device__ __forceinline__ float bf2f(unsigned short h) {
    return __uint_as_float(((unsigned)h) << 16);
}

// padded LDS index (float2 units): insert 1 pad per 8 -> breaks pow2 strides
#define PADI(i) ((i) + ((i) >> 3))

__device__ __forceinline__ float2 cmul(float2 a, float2 b) {
    return make_float2(a.x * b.x - a.y * b.y, a.x * b.y + a.y * b.x);
}

// ---------------- kernel 1: sketch + radix-8 FFT + product + IFFT ----------
// SGN = -1 forward, +1 inverse. Twiddles on the fly (dyadic-exact args).
template<int SGN>
__device__ __forceinline__ void radix8_stage(const float2* __restrict__ src,
                                             float2* __restrict__ dst,
                                             int ns, int tid)
{
    float2 z[8];
#pragma unroll
    for (int k = 0; k < 8; ++k) z[k] = src[PADI(tid + k * 1024)];

    const int j = tid & (ns - 1);
    const float ang = (float)SGN * 6.28318530717958647692f * ((float)j / (float)(8 * ns));
    float sn, cs;
    __sincosf(ang, &sn, &cs);
    float2 w1 = make_float2(cs, sn);
    float2 w2 = cmul(w1, w1), w3 = cmul(w2, w1), w4 = cmul(w2, w2);
    float2 w5 = cmul(w4, w1), w6 = cmul(w4, w2), w7 = cmul(w4, w3);

    float2 u0 = z[0],           u1 = cmul(z[1], w1), u2 = cmul(z[2], w2), u3 = cmul(z[3], w3);
    float2 u4 = cmul(z[4], w4), u5 = cmul(z[5], w5), u6 = cmul(z[6], w6), u7 = cmul(z[7], w7);

    const float sg = (float)SGN;
    // even 4-DFT on (u0,u2,u4,u6)
    float2 t0 = make_float2(u0.x + u4.x, u0.y + u4.y);
    float2 t1 = make_float2(u0.x - u4.x, u0.y - u4.y);
    float2 t2 = make_float2(u2.x + u6.x, u2.y + u6.y);
    float2 t3 = make_float2(u2.x - u6.x, u2.y - u6.y);
    float2 E0 = make_float2(t0.x + t2.x, t0.y + t2.y);
    float2 E2 = make_float2(t0.x - t2.x, t0.y - t2.y);
    float2 E1 = make_float2(t1.x - sg * t3.y, t1.y + sg * t3.x);
    float2 E3 = make_float2(t1.x + sg * t3.y, t1.y - sg * t3.x);
    // odd 4-DFT on (u1,u3,u5,u7)
    float2 s0 = make_float2(u1.x + u5.x, u1.y + u5.y);
    float2 s1 = make_float2(u1.x - u5.x, u1.y - u5.y);
    float2 s2 = make_float2(u3.x + u7.x, u3.y + u7.y);
    float2 s3 = make_float2(u3.x - u7.x, u3.y - u7.y);
    float2 O0 = make_float2(s0.x + s2.x, s0.y + s2.y);
    float2 O2 = make_float2(s0.x - s2.x, s0.y - s2.y);
    float2 O1 = make_float2(s1.x - sg * s3.y, s1.y + sg * s3.x);
    float2 O3 = make_float2(s1.x + sg * s3.y, s1.y - sg * s3.x);
    // twist odd by w8^m, w8 = exp(SGN*2pi*i/8)
    const float C8 = 0.70710678118654752440f;
    float2 P1 = make_float2(C8 * (O1.x - sg * O1.y), C8 * (O1.y + sg * O1.x));
    float2 P2 = make_float2(-sg * O2.y, sg * O2.x);
    float2 P3 = make_float2(C8 * (-O3.x - sg * O3.y), C8 * (sg * O3.x - O3.y));

    const int base = 8 * tid - 7 * j;   // = 8*(tid-j) + j
    dst[PADI(base + 0 * ns)] = make_float2(E0.x + O0.x, E0.y + O0.y);
    dst[PADI(base + 1 * ns)] = make_float2(E1.x + P1.x, E1.y + P1.y);
    dst[PADI(base + 2 * ns)] = make_float2(E2.x + P2.x, E2.y + P2.y);
    dst[PADI(base + 3 * ns)] = make_float2(E3.x + P3.x, E3.y + P3.y);
    dst[PADI(base + 4 * ns)] = make_float2(E0.x - O0.x, E0.y - O0.y);
    dst[PADI(base + 5 * ns)] = make_float2(E1.x - P1.x, E1.y - P1.y);
    dst[PADI(base + 6 * ns)] = make_float2(E2.x - P2.x, E2.y - P2.y);
    dst[PADI(base + 7 * ns)] = make_float2(E3.x - P3.x, E3.y - P3.y);
}

template<int SGN>
__device__ __forceinline__ void radix2_final(const float2* __restrict__ src,
                                             float2* __restrict__ dst, int tid)
{
#pragma unroll
    for (int it = 0; it < 4; ++it) {
        int i = tid + it * 1024;
        float2 a = src[PADI(i)];
        float2 c = src[PADI(i + 4096)];
        float ang = (float)SGN * 6.28318530717958647692f * ((float)i * (1.0f / 8192.0f));
        float sn, cs;
        __sincosf(ang, &sn, &cs);
        float2 wc = make_float2(cs * c.x - sn * c.y, cs * c.y + sn * c.x);
        dst[PADI(i)]        = make_float2(a.x + wc.x, a.y + wc.y);
        dst[PADI(i + 4096)] = make_float2(a.x - wc.x, a.y - wc.y);
    }
}

__global__ __launch_bounds__(1024) void cbp_kernel(
    const float* __restrict__ x, const int* __restrict__ h1, const int* __restrict__ h2,
    const float* __restrict__ s1, const float* __restrict__ s2,
    unsigned short* __restrict__ Ah, unsigned short* __restrict__ Al)
{
    __shared__ float2 bufA[9216];   // PADI(8192)
    __shared__ float2 bufB[9216];
    const int b = blockIdx.x;
    const int tid = threadIdx.x;

    for (int i = tid; i < 9216; i += 1024) bufA[i] = make_float2(0.f, 0.f);
    __syncthreads();

    // count-sketch scatter (sk1 in .x, sk2 in .y)
    const float* xrow = x + (size_t)b * FIN;
#pragma unroll
    for (int it = 0; it < 2; ++it) {
        int i = tid + it * 1024;
        float v = xrow[i];
        atomicAdd(&bufA[PADI(h1[i])].x, s1[i] * v);
        atomicAdd(&bufA[PADI(h2[i])].y, s2[i] * v);
    }
    __syncthreads();

    // forward FFT: 4 radix-8 + 1 radix-2 stages
    radix8_stage<-1>(bufA, bufB, 1, tid);   __syncthreads();
    radix8_stage<-1>(bufB, bufA, 8, tid);   __syncthreads();
    radix8_stage<-1>(bufA, bufB, 64, tid);  __syncthreads();
    radix8_stage<-1>(bufB, bufA, 512, tid); __syncthreads();
    radix2_final<-1>(bufA, bufB, tid);      __syncthreads();

    // Hermitian split + pointwise product P = F1 * F2 (bufB -> bufA)
#pragma unroll
    for (int it = 0; it < 8; ++it) {
        int k = tid + it * 1024;
        float2 zk = bufB[PADI(k)];
        float2 zm = bufB[PADI((8192 - k) & 8191)];
        float f1x = 0.5f * (zk.x + zm.x);
        float f1y = 0.5f * (zk.y - zm.y);
        float gx  = 0.5f * (zk.x - zm.x);
        float gy  = 0.5f * (zk.y + zm.y);
        float f2x = gy, f2y = -gx;   // F2 = -i*(gx + i*gy)
        bufA[PADI(k)] = make_float2(f1x * f2x - f1y * f2y, f1x * f2y + f1y * f2x);
    }
    __syncthreads();

    // inverse FFT
    radix8_stage<1>(bufA, bufB, 1, tid);   __syncthreads();
    radix8_stage<1>(bufB, bufA, 8, tid);   __syncthreads();
    radix8_stage<1>(bufA, bufB, 64, tid);  __syncthreads();
    radix8_stage<1>(bufB, bufA, 512, tid); __syncthreads();
    radix2_final<1>(bufA, bufB, tid);      __syncthreads();

    // cbp row = Re/D; split-bf16 emit
    const float invD = 1.0f / 8192.0f;
    unsigned short* ah = Ah + (size_t)b * D;
    unsigned short* al = Al + (size_t)b * D;
#pragma unroll
    for (int it = 0; it < 8; ++it) {
        int t = tid + it * 1024;
        float v = bufB[PADI(t)].x * invD;
        unsigned short h = f2bf(v);
        unsigned short l = f2bf(v - bf2f(h));
        ah[t] = h;
        al[t] = l;
    }
}

// ---------------- kernel 2: GEMM out[m,n] = sum_k cbp[m,k]*W[n,k] + b[n] ----
// BM=128, BN=64, KS=64; 512 thr / 8 waves (4M x 2N), wave tile 32x32.
// A (bf16 hi+lo) via global_load_lds, double-buffered, XOR-swizzled (pre-swizzled
// global source per rule #21). W f32 -> bf16 hi/lo reg-staged into swizzled LDS.
// 3-term split: Ah*Bh + Ah*Bl + Al*Bh.
#define BM 128
#define BN 64
#define KS 64

__global__ __launch_bounds__(512, 4) void gemm_kernel(
    const unsigned short* __restrict__ Ah, const unsigned short* __restrict__ Al,
    const float* __restrict__ W, const float* __restrict__ bias,
    float* __restrict__ out)
{
    __shared__ __align__(16) unsigned short lA[2][2][BM * KS];  // [buf][hi/lo] 64 KB
    __shared__ __align__(16) unsigned short lB[2][BN * KS];     // [hi/lo]      16 KB

    const int tid = threadIdx.x;
    const int wave = tid >> 6;
    const int lane = tid & 63;
    const int wm = wave >> 1;     // 0..3 -> rows 32*wm
    const int wn = wave & 1;      // 0..1 -> cols 32*wn
    const int r16 = lane & 15;
    const int q8  = (lane >> 4) * 8;

    // bijective XCD swizzle over 468 blocks (8 XCDs, chunks 59x4 + 58x4);
    // consecutive wg = the two m-halves of one n-tile -> same XCD, W L2 reuse.
    const int orig = blockIdx.x;
    const int xcd = orig & 7, idx = orig >> 3;
    const int wg = (xcd < 4 ? xcd * 59 : 236 + (xcd - 4) * 58) + idx;
    const int n0 = (wg >> 1) * BN;
    const int m0 = (wg & 1) * BM;

    // B staging decomposition: thread -> (row bn, 16B chunk tid&7)
    const int bn = tid >> 3;
    const int bk8 = (tid & 7) * 8;   // f32 element offset

    f32x4 acc[2][2];
#pragma unroll
    for (int i = 0; i < 2; ++i)
#pragma unroll
        for (int jj = 0; jj < 2; ++jj) acc[i][jj] = (f32x4){0.f, 0.f, 0.f, 0.f};

    float4 pbw0, pbw1;

    auto LOADW = [&](int k0) {
        const int n = n0 + bn;
        if (n < NC) {
            const float4* gw = reinterpret_cast<const float4*>(W + (size_t)n * D + k0 + bk8);
            pbw0 = gw[0];
            pbw1 = gw[1];
        } else {
            pbw0 = make_float4(0.f, 0.f, 0.f, 0.f);
            pbw1 = make_float4(0.f, 0.f, 0.f, 0.f);
        }
    };

    auto STOREB = [&]() {
        float pf[8] = {pbw0.x, pbw0.y, pbw0.z, pbw0.w, pbw1.x, pbw1.y, pbw1.z, pbw1.w};
        unsigned short h[8], l[8];
#pragma unroll
        for (int jj = 0; jj < 8; ++jj) {
            h[jj] = f2bf(pf[jj]);
            l[jj] = f2bf(pf[jj] - bf2f(h[jj]));
        }
        uint4 hv, lv;
        hv.x = (unsigned)h[0] | ((unsigned)h[1] << 16);
        hv.y = (unsigned)h[2] | ((unsigned)h[3] << 16);
        hv.z = (unsigned)h[4] | ((unsigned)h[5] << 16);
        hv.w = (unsigned)h[6] | ((unsigned)h[7] << 16);
        lv.x = (unsigned)l[0] | ((unsigned)l[1] << 16);
        lv.y = (unsigned)l[2] | ((unsigned)l[3] << 16);
        lv.z = (unsigned)l[4] | ((unsigned)l[5] << 16);
        lv.w = (unsigned)l[6] | ((unsigned)l[7] << 16);
        const int byteoff = (bn * 128 + (tid & 7) * 16) ^ ((bn & 7) << 4);
        *reinterpret_cast<uint4*>((char*)&lB[0][0] + byteoff) = hv;
        *reinterpret_cast<uint4*>((char*)&lB[1][0] + byteoff) = lv;
    };

    // A stage: per wave 2 chunks of 1 KB per plane; LDS dest linear (gload_lds
    // writes base+lane*16), global source pre-swizzled with the same XOR the
    // reads use (rule #21: same involution on source and read side).
    auto STAGE_A = [&](int k0, int buf) {
#pragma unroll
        for (int p = 0; p < 2; ++p) {
            const unsigned short* gp = p ? Al : Ah;
#pragma unroll
            for (int c = 0; c < 2; ++c) {
                const int T = (wave * 2 + c) * 64 + lane;    // 16B-chunk id
                const int row = T >> 3;
                const int lcol = (T & 7) ^ (row & 7);
                const unsigned short* src = gp + (size_t)(m0 + row) * D + k0 + lcol * 8;
                char* dst = (char*)&lA[buf][p][0] + (wave * 2 + c) * 1024;
                __builtin_amdgcn_global_load_lds(
                    (const __attribute__((address_space(1))) void*)src,
                    (__attribute__((address_space(3))) void*)dst, 16, 0, 0);
            }
        }
    };

    auto COMPUTE = [&](int buf) {
#pragma unroll
        for (int ksub = 0; ksub < 2; ++ksub) {
            const int keb = (ksub * 32 + q8) * 2;   // byte offset of k-chunk
            short8 a_hi[2], a_lo[2], b_hi[2], b_lo[2];
#pragma unroll
            for (int rb = 0; rb < 2; ++rb) {
                const int row = wm * 32 + rb * 16 + r16;
                const int bo = (row * 128 + keb) ^ ((row & 7) << 4);
                a_hi[rb] = *reinterpret_cast<const short8*>((const char*)&lA[buf][0][0] + bo);
                a_lo[rb] = *reinterpret_cast<const short8*>((const char*)&lA[buf][1][0] + bo);
            }
#pragma unroll
            for (int nb = 0; nb < 2; ++nb) {
                const int row = wn * 32 + nb * 16 + r16;
                const int bo = (row * 128 + keb) ^ ((row & 7) << 4);
                b_hi[nb] = *reinterpret_cast<const short8*>((const char*)&lB[0][0] + bo);
                b_lo[nb] = *reinterpret_cast<const short8*>((const char*)&lB[1][0] + bo);
            }
#pragma unroll
            for (int rb = 0; rb < 2; ++rb)
#pragma unroll
                for (int nb = 0; nb < 2; ++nb) {
                    acc[rb][nb] = __builtin_amdgcn_mfma_f32_16x16x32_bf16(a_hi[rb], b_hi[nb], acc[rb][nb], 0, 0, 0);
                    acc[rb][nb] = __builtin_amdgcn_mfma_f32_16x16x32_bf16(a_hi[rb], b_lo[nb], acc[rb][nb], 0, 0, 0);
                    acc[rb][nb] = __builtin_amdgcn_mfma_f32_16x16x32_bf16(a_lo[rb], b_hi[nb], acc[rb][nb], 0, 0, 0);
                }
        }
    };

    // pipeline: A(k+1)+W(k+1) prefetched during compute(k); A double-buffered.
    LOADW(0);
    STAGE_A(0, 0);
    int buf = 0;
    for (int k0 = 0; k0 < D; k0 += KS) {
        __syncthreads();             // b1: prev compute done; A(k0)/W(k0) drained
        STOREB();                    // B(k0) regs -> LDS
        __syncthreads();             // b2: B visible
        if (k0 + KS < D) {
            STAGE_A(k0 + KS, buf ^ 1);   // flies under compute
            LOADW(k0 + KS);              // flies under compute
        }
        COMPUTE(buf);
        buf ^= 1;
    }

    // epilogue: C/D map col = lane&15, row = (lane>>4)*4 + reg
    const int rq = (lane >> 4) * 4;
#pragma unroll
    for (int nb = 0; nb < 2; ++nb) {
        const int nc = n0 + wn * 32 + nb * 16 + r16;
        if (nc < NC) {
            const float bv = bias[nc];
#pragma unroll
            for (int rb = 0; rb < 2; ++rb)
#pragma unroll
                for (int r = 0; r < 4; ++r) {
                    const int m = m0 + wm * 32 + rb * 16 + rq + r;
                    out[(size_t)m * NC + nc] = acc[rb][nb][r] + bv;
                }
        }
    }
}

extern "C" void kernel_launch(void* const* d_in, const int* in_sizes, int n_in,
                              void* d_out, int out_size, void* d_ws, size_t ws_size,
                              hipStream_t stream) {
    (void)in_sizes; (void)n_in; (void)out_size;
    const float* x  = (const float*)d_in[0];
    const int*   h1 = (const int*)d_in[1];
    const int*   h2 = (const int*)d_in[2];
    const float* s1 = (const float*)d_in[3];
    const float* s2 = (const float*)d_in[4];
    const float* W  = (const float*)d_in[5];
    const float* bias = (const float*)d_in[6];
    float* out = (float*)d_out;

    const size_t A_BYTES = (size_t)BATCH * D * sizeof(unsigned short);  // 4 MB
    if (ws_size < 2 * A_BYTES) return;

    unsigned short* Ah = (unsigned short*)d_ws;
    unsigned short* Al = (unsigned short*)((char*)d_ws + A_BYTES);

    cbp_kernel<<<dim3(BATCH), dim3(1024), 0, stream>>>(x, h1, h2, s1, s2, Ah, Al);
    const int nblocks = ((NC + BN - 1) / BN) * 2;   // 234 n-tiles x 2 m-halves = 468
    gemm_kernel<<<dim3(nblocks), dim3(512), 0, stream>>>(Ah, Al, W, bias, out);
}